// Round 6
// baseline (1716.632 us; speedup 1.0000x reference)
//
#include <hip/hip_runtime.h>

#define NRELS 8
typedef __attribute__((ext_vector_type(8))) short s16x8;
typedef __attribute__((ext_vector_type(4))) float f32x4;
typedef unsigned short u16;
typedef unsigned int u32;

__device__ __forceinline__ u16 f2bf(float v) {
    unsigned u = __float_as_uint(v);
    u += 0x7FFFu + ((u >> 16) & 1u);
    return (u16)(u >> 16);
}
__device__ __forceinline__ float bf2f(u16 h) {
    return __uint_as_float(((unsigned)h) << 16);
}
__device__ __forceinline__ float eluf(float x) { return x > 0.f ? x : __expf(x) - 1.f; }

// ---------------- weight prep: fragment-major bf16 W (9 col-tiles) + permuted bias ----
__global__ void prep_weights(const float* __restrict__ Ws1, const float* __restrict__ Wd1,
                             const float* __restrict__ as1, const float* __restrict__ ad1,
                             const float* __restrict__ b1,
                             const float* __restrict__ Ws2, const float* __restrict__ Wd2,
                             const float* __restrict__ as2, const float* __restrict__ ad2,
                             const float* __restrict__ b2,
                             u16* __restrict__ Wfrag, float* __restrict__ bperm) {
    const int bid = blockIdx.x;
    const int layer = bid >> 3, r = bid & 7, r1 = r ^ 1;
    const float* Ws  = (layer ? Ws2 : Ws1) + (size_t)r  * 16384;
    const float* asp = (layer ? as2 : as1) + r  * 128;
    const float* Wdr = (layer ? Wd2 : Wd1) + (size_t)r1 * 16384;
    const float* adr = (layer ? ad2 : ad1) + r1 * 128;
    const float* bb  = (layer ? b2  : b1 ) + r  * 128;
    u16* wf = Wfrag + (size_t)bid * 18432;
    for (int f = threadIdx.x; f < 18432; f += blockDim.x) {
        int be   = f & 7;
        int lane = (f >> 3) & 63;
        int kc   = (f >> 9) & 3;
        int ct   = f >> 11;
        int k    = kc * 32 + (lane >> 4) * 8 + be;
        int krow = layer ? (((k & 7) << 4) | (k >> 3)) : k;
        int c    = lane & 15;
        float val;
        if (ct < 8) {
            val = Ws[(size_t)krow * 128 + ct * 16 + c];
        } else if (c < 4) {
            float s = 0.f;
            #pragma unroll
            for (int cc = 0; cc < 32; ++cc) s += Ws[(size_t)krow * 128 + c * 32 + cc] * asp[c * 32 + cc];
            val = s;
        } else if (c < 8) {
            int h = c - 4;
            float s = 0.f;
            #pragma unroll
            for (int cc = 0; cc < 32; ++cc) s += Wdr[(size_t)krow * 128 + h * 32 + cc] * adr[h * 32 + cc];
            val = s;
        } else {
            val = 0.f;
        }
        wf[f] = f2bf(val);
    }
    if (threadIdx.x < 128) {
        int p = threadIdx.x;
        bperm[bid * 128 + p] = bb[((p & 7) << 4) | (p >> 3)];
    }
}

// ---------------- fp32 -> bf16 convert (8 elems/thread) ----------------
__global__ void conv_bf16(const float* __restrict__ in, u16* __restrict__ out, long n8) {
    long i = (long)blockIdx.x * blockDim.x + threadIdx.x;
    if (i >= n8) return;
    float4 v0 = ((const float4*)in)[i * 2];
    float4 v1 = ((const float4*)in)[i * 2 + 1];
    union { u16 u[8]; uint4 q; } pk;
    pk.u[0] = f2bf(v0.x); pk.u[1] = f2bf(v0.y); pk.u[2] = f2bf(v0.z); pk.u[3] = f2bf(v0.w);
    pk.u[4] = f2bf(v1.x); pk.u[5] = f2bf(v1.y); pk.u[6] = f2bf(v1.z); pk.u[7] = f2bf(v1.w);
    ((uint4*)out)[i] = pk.q;
}

// ---------------- batched MFMA GEMM (grid.y = relation in batch) ----------------
__global__ __launch_bounds__(256) void gemm_mfma(const u16* __restrict__ Xbf,
                                                 const u16* __restrict__ WfragL,
                                                 u16* __restrict__ Hs4,
                                                 float* __restrict__ es4,
                                                 float* __restrict__ ed4,
                                                 int rbase, int4 st, int N) {
    const int y = blockIdx.y;
    const int r = rbase + y;
    const int stype = (y == 0) ? st.x : (y == 1) ? st.y : (y == 2) ? st.z : st.w;
    const u16* X  = Xbf + (size_t)stype * N * 128;
    const u16* Wf = WfragL + (size_t)r * 18432;
    u16*   Hs = Hs4 + (size_t)(r & 3) * N * 128;
    float* es = es4 + (size_t)(r & 3) * N * 4;
    float* ed = ed4 + (size_t)((r ^ 1) & 3) * N * 4;

    __shared__ u16 wlds[18432];
    const int tid = threadIdx.x;
    for (int i = tid; i < 2304; i += 256)
        ((s16x8*)wlds)[i] = ((const s16x8*)Wf)[i];

    const int wv = tid >> 6, l = tid & 63;
    const int lr = l & 15, lk = l >> 4;
    const int r0 = blockIdx.x * 128 + wv * 32;

    s16x8 af[2][4];
    #pragma unroll
    for (int rt = 0; rt < 2; ++rt) {
        int row = r0 + rt * 16 + lr;
        if (row > N - 1) row = N - 1;
        const s16x8* xp = (const s16x8*)(X + (size_t)row * 128 + lk * 8);
        af[rt][0] = xp[0]; af[rt][1] = xp[4]; af[rt][2] = xp[8]; af[rt][3] = xp[12];
    }
    __syncthreads();

    f32x4 acc[2][9] = {};
    #pragma unroll
    for (int ct = 0; ct < 9; ++ct) {
        s16x8 bf0 = ((s16x8*)wlds)[(ct * 4 + 0) * 64 + l];
        s16x8 bf1 = ((s16x8*)wlds)[(ct * 4 + 1) * 64 + l];
        s16x8 bf2 = ((s16x8*)wlds)[(ct * 4 + 2) * 64 + l];
        s16x8 bf3 = ((s16x8*)wlds)[(ct * 4 + 3) * 64 + l];
        #pragma unroll
        for (int rt = 0; rt < 2; ++rt) {
            acc[rt][ct] = __builtin_amdgcn_mfma_f32_16x16x32_bf16(af[rt][0], bf0, acc[rt][ct], 0, 0, 0);
            acc[rt][ct] = __builtin_amdgcn_mfma_f32_16x16x32_bf16(af[rt][1], bf1, acc[rt][ct], 0, 0, 0);
            acc[rt][ct] = __builtin_amdgcn_mfma_f32_16x16x32_bf16(af[rt][2], bf2, acc[rt][ct], 0, 0, 0);
            acc[rt][ct] = __builtin_amdgcn_mfma_f32_16x16x32_bf16(af[rt][3], bf3, acc[rt][ct], 0, 0, 0);
        }
    }

    #pragma unroll
    for (int rt = 0; rt < 2; ++rt) {
        #pragma unroll
        for (int j = 0; j < 4; ++j) {
            int row = r0 + rt * 16 + lk * 4 + j;
            if (row < N) {
                union { u16 u[8]; uint4 q; } pk;
                #pragma unroll
                for (int ct = 0; ct < 8; ++ct) pk.u[ct] = f2bf(acc[rt][ct][j]);
                *(uint4*)(Hs + (size_t)row * 128 + lr * 8) = pk.q;
                float evv = acc[rt][8][j];
                if (lr < 4)      es[(size_t)row * 4 + lr]     = evv;
                else if (lr < 8) ed[(size_t)row * 4 + lr - 4] = evv;
            }
        }
    }
}

// ---------------- CSR build (XCD-local: blockIdx%8 = relation) ----------------
__global__ void hist_kernel(const int* __restrict__ edges, int* __restrict__ counts,
                            int E, int N) {
    int r = blockIdx.x & 7;
    int e = (blockIdx.x >> 3) * 256 + threadIdx.x;
    if (e >= E) return;
    int d = edges[(size_t)r * 2 * E + E + e];
    atomicAdd(&counts[r * N + d], 1);
}

__global__ __launch_bounds__(256) void scan_block_k(const int* __restrict__ in,
                                                    int* __restrict__ outv,
                                                    int* __restrict__ bsum, int M) {
    __shared__ int sh[256];
    int t = threadIdx.x;
    int base = blockIdx.x * 2048 + t * 8;
    int vals[8];
    int tot = 0;
    #pragma unroll
    for (int j = 0; j < 8; ++j) {
        int v = (base + j < M) ? in[base + j] : 0;
        vals[j] = tot; tot += v;
    }
    sh[t] = tot;
    __syncthreads();
    for (int ofs = 1; ofs < 256; ofs <<= 1) {
        int y = 0;
        if (t >= ofs) y = sh[t - ofs];
        __syncthreads();
        if (t >= ofs) sh[t] += y;
        __syncthreads();
    }
    int ex = (t == 0) ? 0 : sh[t - 1];
    #pragma unroll
    for (int j = 0; j < 8; ++j)
        if (base + j < M) outv[base + j] = ex + vals[j];
    if (t == 255) bsum[blockIdx.x] = sh[255];
}

__global__ __launch_bounds__(1024) void scan_tops_k(const int* __restrict__ bsum,
                                                    int* __restrict__ bpref, int nb) {
    __shared__ int sh[1024];
    int t = threadIdx.x;
    int v = (t < nb) ? bsum[t] : 0;
    sh[t] = v;
    __syncthreads();
    for (int ofs = 1; ofs < 1024; ofs <<= 1) {
        int y = 0;
        if (t >= ofs) y = sh[t - ofs];
        __syncthreads();
        if (t >= ofs) sh[t] += y;
        __syncthreads();
    }
    if (t < nb) bpref[t] = sh[t] - v;
}

__global__ void scan_add_k(int* __restrict__ outv, const int* __restrict__ bpref, int M) {
    int g = blockIdx.x * blockDim.x + threadIdx.x;
    if (g < M) outv[g] += bpref[g >> 11];
}

__global__ void build_csr_k(const int* __restrict__ edges, int* __restrict__ pos,
                            int* __restrict__ srcs, int E, int N) {
    int r = blockIdx.x & 7;
    int e = (blockIdx.x >> 3) * 256 + threadIdx.x;
    if (e >= E) return;
    const int* b = edges + (size_t)r * 2 * E;
    int s = b[e], d = b[E + e];
    int idx = atomicAdd(&pos[r * N + d], 1);
    srcs[idx] = s;
}

// ---------------- fused gather (serial small-degree path) ----------------
// OUT_MODE: 0 = ELU->bf16 (perm layout, to Xbf slice)
//           1 = raw fp32 perm (partial scratch)
//           2 = ELU fp32 un-permuted (final d_out slice)
// ACC: add partial scratch (perm fp32) before epilogue
template<int NR, int OUT_MODE, int ACC>
__global__ __launch_bounds__(256) void gat_gather(
        const int* __restrict__ srcsG,
        const int* __restrict__ offA, const int* __restrict__ cntA,
        const float* __restrict__ esA, const float* __restrict__ edA,
        const u16* __restrict__ HsA, const float* __restrict__ bpA,
        const int* __restrict__ offB, const int* __restrict__ cntB,
        const float* __restrict__ esB, const float* __restrict__ edB,
        const u16* __restrict__ HsB, const float* __restrict__ bpB,
        void* __restrict__ outA, void* __restrict__ outB,
        const float* __restrict__ part, int N) {
    const int lane = threadIdx.x & 63;
    const int d    = (blockIdx.x * 256 + threadIdx.x) >> 6;
    if (d >= N) return;
    const int h = lane & 3;
    const int pick = (NR == 1) ? blockIdx.y : 0;

    float a0 = 0.f, a1 = 0.f;

    #pragma unroll
    for (int rr = 0; rr < NR; ++rr) {
        const bool useB = (NR == 2) ? (rr == 1) : (pick == 1);
        const int* OFF  = useB ? offB : offA;
        const int* CNT  = useB ? cntB : cntA;
        const float* ES = useB ? esB  : esA;
        const float* ED = useB ? edB  : edA;
        const u16* HS   = useB ? HsB  : HsA;

        const int o0 = OFF[d], dg = CNT[d];
        if (dg == 0) continue;
        const float edv = ED[(size_t)d * 4 + h];

        // pass 1: cache first 8 edges in registers (statically indexed),
        // compute true segment max; serial tail for rare dg>8.
        int   sc[8];
        float lc[8];
        float mx = -INFINITY;
        #pragma unroll
        for (int i = 0; i < 8; ++i) {
            if (i < dg) {
                int s = srcsG[o0 + i];
                float lv = ES[(size_t)s * 4 + h] + edv;
                lv = lv > 0.f ? lv : 0.2f * lv;
                sc[i] = s; lc[i] = lv;
                mx = fmaxf(mx, lv);
            }
        }
        for (int i = 8; i < dg; ++i) {
            int s = srcsG[o0 + i];
            float lv = ES[(size_t)s * 4 + h] + edv;
            lv = lv > 0.f ? lv : 0.2f * lv;
            mx = fmaxf(mx, lv);
        }

        // pass 2: exp, denom, weighted coalesced Hs gather
        float den = 0.f, r0 = 0.f, r1 = 0.f;
        #pragma unroll
        for (int i = 0; i < 8; ++i) {
            if (i < dg) {
                float p = __expf(lc[i] - mx);
                den += p;
                u32 hv = *(const u32*)(HS + (size_t)sc[i] * 128 + 2 * lane);
                r0 += p * bf2f((u16)(hv & 0xFFFF));
                r1 += p * bf2f((u16)(hv >> 16));
            }
        }
        for (int i = 8; i < dg; ++i) {
            int s = srcsG[o0 + i];
            float lv = ES[(size_t)s * 4 + h] + edv;
            lv = lv > 0.f ? lv : 0.2f * lv;
            float p = __expf(lv - mx);
            den += p;
            u32 hv = *(const u32*)(HS + (size_t)s * 128 + 2 * lane);
            r0 += p * bf2f((u16)(hv & 0xFFFF));
            r1 += p * bf2f((u16)(hv >> 16));
        }
        float inv = 1.f / (den + 1e-16f);
        a0 += r0 * inv; a1 += r1 * inv;
    }

    const float* bb = (NR == 1 && pick == 1) ? bpB : bpA;
    float b0 = bb[2 * lane], b1v = bb[2 * lane + 1];
    if (NR == 2) { b0 += bpB[2 * lane]; b1v += bpB[2 * lane + 1]; }
    a0 += b0; a1 += b1v;
    if (ACC) {
        float2 pv = *(const float2*)(part + (size_t)d * 128 + 2 * lane);
        a0 += pv.x; a1 += pv.y;
    }
    void* OP = (NR == 1 && pick == 1) ? outB : outA;
    if (OUT_MODE == 0) {
        u32 pk = (u32)f2bf(eluf(a0)) | ((u32)f2bf(eluf(a1)) << 16);
        *(u32*)((u16*)OP + (size_t)d * 128 + 2 * lane) = pk;
    } else if (OUT_MODE == 1) {
        *(float2*)((float*)OP + (size_t)d * 128 + 2 * lane) = make_float2(a0, a1);
    } else {
        float* o = (float*)OP + (size_t)d * 128;
        int p0 = 2 * lane, p1 = 2 * lane + 1;
        o[(p0 >> 3) | ((p0 & 7) << 4)] = eluf(a0);
        o[(p1 >> 3) | ((p1 & 7) << 4)] = eluf(a1);
    }
}

extern "C" void kernel_launch(void* const* d_in, const int* in_sizes, int n_in,
                              void* d_out, int out_size, void* d_ws, size_t ws_size,
                              hipStream_t stream) {
    const int N = in_sizes[0] / 128;
    const int E = in_sizes[5] / (2 * NRELS);

    const float* xs0[5] = { (const float*)d_in[0], (const float*)d_in[1],
                            (const float*)d_in[2], (const float*)d_in[3],
                            (const float*)d_in[4] };
    const int*   edges = (const int*)d_in[5];
    const float* Ws1 = (const float*)d_in[6];
    const float* Wd1 = (const float*)d_in[7];
    const float* as1 = (const float*)d_in[8];
    const float* ad1 = (const float*)d_in[9];
    const float* b1  = (const float*)d_in[10];
    const float* Ws2 = (const float*)d_in[11];
    const float* Wd2 = (const float*)d_in[12];
    const float* as2 = (const float*)d_in[13];
    const float* ad2 = (const float*)d_in[14];
    const float* b2  = (const float*)d_in[15];
    float* out = (float*)d_out;

    // workspace layout (~314 MB)
    char* wp = (char*)d_ws;
    u16*   Xbf   = (u16*)wp;   wp += (size_t)5 * N * 128 * 2;
    u16*   Hs4   = (u16*)wp;   wp += (size_t)4 * N * 128 * 2;
    float* es4   = (float*)wp; wp += (size_t)4 * N * 4 * 4;
    float* ed4   = (float*)wp; wp += (size_t)4 * N * 4 * 4;
    float* part  = (float*)wp; wp += (size_t)N * 128 * 4;
    int* counts  = (int*)wp;   wp += (size_t)NRELS * N * 4;
    int* offs    = (int*)wp;   wp += (size_t)NRELS * N * 4;
    int* pos     = (int*)wp;   wp += (size_t)NRELS * N * 4;
    int* srcs    = (int*)wp;   wp += (size_t)NRELS * E * 4;
    u16* Wfrag   = (u16*)wp;   wp += (size_t)16 * 18432 * 2;
    float* bperm = (float*)wp; wp += (size_t)16 * 128 * 4;
    int* bsum    = (int*)wp;   wp += 1024 * 4;
    int* bpref   = (int*)wp;   wp += 1024 * 4;
    const size_t ws_used = (size_t)(wp - (char*)d_ws);
    if (ws_used > ws_size) return;

    // ---- re-establish the validated zero initial state on EVERY call ----
    hipMemsetAsync(d_ws, 0, ws_used, stream);
    hipMemsetAsync(d_out, 0, (size_t)5 * N * 128 * 4, stream);

    // ---- weight prep ----
    prep_weights<<<dim3(16), 256, 0, stream>>>(Ws1, Wd1, as1, ad1, b1,
                                               Ws2, Wd2, as2, ad2, b2, Wfrag, bperm);

    // ---- build CSR (dst-sorted), XCD-local ----
    const int M  = NRELS * N;
    const int nb = (M + 2047) / 2048;
    const int eblocks = 8 * ((E + 255) / 256);
    hist_kernel<<<dim3(eblocks), 256, 0, stream>>>(edges, counts, E, N);
    scan_block_k<<<dim3(nb), 256, 0, stream>>>(counts, offs, bsum, M);
    scan_tops_k<<<dim3(1), 1024, 0, stream>>>(bsum, bpref, nb);
    scan_add_k<<<dim3((M + 255) / 256), 256, 0, stream>>>(offs, bpref, M);
    hipMemcpyAsync(pos, offs, (size_t)M * 4, hipMemcpyDeviceToDevice, stream);
    build_csr_k<<<dim3(eblocks), 256, 0, stream>>>(edges, pos, srcs, E, N);

    // ---- convert inputs to bf16 ----
    const long n8type = (long)N * 128 / 8;
    for (int t = 0; t < 5; ++t)
        conv_bf16<<<dim3((int)((n8type + 255) / 256)), 256, 0, stream>>>(
            xs0[t], Xbf + (size_t)t * N * 128, n8type);

    const int gemmBlocks = (N + 127) / 128;
    const int gBlocks    = (N + 3) / 4;

    // per-relation slot helpers
    #define OFFR(r)  (offs   + (size_t)(r) * N)
    #define CNTR(r)  (counts + (size_t)(r) * N)
    #define ESR(r)   (es4 + (size_t)((r) & 3) * N * 4)
    #define EDR(r)   (ed4 + (size_t)((r) & 3) * N * 4)
    #define HSR(r)   (Hs4 + (size_t)((r) & 3) * N * 128)

    for (int layer = 0; layer < 2; ++layer) {
        const u16*   WL = Wfrag + (size_t)layer * 8 * 18432;
        const float* bL = bperm + layer * 8 * 128;

        // ===== batch A: relations 0..3 (src types 0,1,0,2) =====
        gemm_mfma<<<dim3(gemmBlocks, 4), 256, 0, stream>>>(
            Xbf, WL, Hs4, es4, ed4, 0, make_int4(0, 1, 0, 2), N);
        // singles: r0 -> dst type 1, r2 -> dst type 2
        if (layer == 0)
            gat_gather<1, 0, 0><<<dim3(gBlocks, 2), 256, 0, stream>>>(
                srcs, OFFR(0), CNTR(0), ESR(0), EDR(0), HSR(0), bL + 0 * 128,
                OFFR(2), CNTR(2), ESR(2), EDR(2), HSR(2), bL + 2 * 128,
                Xbf + (size_t)1 * N * 128, Xbf + (size_t)2 * N * 128, nullptr, N);
        else
            gat_gather<1, 2, 0><<<dim3(gBlocks, 2), 256, 0, stream>>>(
                srcs, OFFR(0), CNTR(0), ESR(0), EDR(0), HSR(0), bL + 0 * 128,
                OFFR(2), CNTR(2), ESR(2), EDR(2), HSR(2), bL + 2 * 128,
                out + (size_t)1 * N * 128, out + (size_t)2 * N * 128, nullptr, N);
        // fused r1,r3 -> dst type 0 partial (perm fp32)
        gat_gather<2, 1, 0><<<dim3(gBlocks, 1), 256, 0, stream>>>(
            srcs, OFFR(1), CNTR(1), ESR(1), EDR(1), HSR(1), bL + 1 * 128,
            OFFR(3), CNTR(3), ESR(3), EDR(3), HSR(3), bL + 3 * 128,
            part, nullptr, nullptr, N);

        // ===== batch B: relations 4..7 (src types 0,3,0,4) =====
        gemm_mfma<<<dim3(gemmBlocks, 4), 256, 0, stream>>>(
            Xbf, WL, Hs4, es4, ed4, 4, make_int4(0, 3, 0, 4), N);
        // singles: r4 -> dst type 3, r6 -> dst type 4
        if (layer == 0)
            gat_gather<1, 0, 0><<<dim3(gBlocks, 2), 256, 0, stream>>>(
                srcs, OFFR(4), CNTR(4), ESR(4), EDR(4), HSR(4), bL + 4 * 128,
                OFFR(6), CNTR(6), ESR(6), EDR(6), HSR(6), bL + 6 * 128,
                Xbf + (size_t)3 * N * 128, Xbf + (size_t)4 * N * 128, nullptr, N);
        else
            gat_gather<1, 2, 0><<<dim3(gBlocks, 2), 256, 0, stream>>>(
                srcs, OFFR(4), CNTR(4), ESR(4), EDR(4), HSR(4), bL + 4 * 128,
                OFFR(6), CNTR(6), ESR(6), EDR(6), HSR(6), bL + 6 * 128,
                out + (size_t)3 * N * 128, out + (size_t)4 * N * 128, nullptr, N);
        // fused r5,r7 + partial -> dst type 0
        if (layer == 0)
            gat_gather<2, 0, 1><<<dim3(gBlocks, 1), 256, 0, stream>>>(
                srcs, OFFR(5), CNTR(5), ESR(5), EDR(5), HSR(5), bL + 5 * 128,
                OFFR(7), CNTR(7), ESR(7), EDR(7), HSR(7), bL + 7 * 128,
                Xbf + (size_t)0 * N * 128, nullptr, part, N);
        else
            gat_gather<2, 2, 1><<<dim3(gBlocks, 1), 256, 0, stream>>>(
                srcs, OFFR(5), CNTR(5), ESR(5), EDR(5), HSR(5), bL + 5 * 128,
                OFFR(7), CNTR(7), ESR(7), EDR(7), HSR(7), bL + 7 * 128,
                out + (size_t)0 * N * 128, nullptr, part, N);
    }
    #undef OFFR
    #undef CNTR
    #undef ESR
    #undef EDR
    #undef HSR
}

// Round 7
// 1504.335 us; speedup vs baseline: 1.1411x; 1.1411x over previous
//
#include <hip/hip_runtime.h>

#define NRELS 8
typedef __attribute__((ext_vector_type(8))) short s16x8;
typedef __attribute__((ext_vector_type(4))) float f32x4;
typedef unsigned short u16;
typedef unsigned int u32;

__device__ __forceinline__ u16 f2bf(float v) {
    unsigned u = __float_as_uint(v);
    u += 0x7FFFu + ((u >> 16) & 1u);
    return (u16)(u >> 16);
}
__device__ __forceinline__ float bf2f(u16 h) {
    return __uint_as_float(((unsigned)h) << 16);
}
__device__ __forceinline__ float eluf(float x) { return x > 0.f ? x : __expf(x) - 1.f; }

// ---------------- weight prep: fragment-major bf16 W (9 col-tiles) + permuted bias ----
__global__ void prep_weights(const float* __restrict__ Ws1, const float* __restrict__ Wd1,
                             const float* __restrict__ as1, const float* __restrict__ ad1,
                             const float* __restrict__ b1,
                             const float* __restrict__ Ws2, const float* __restrict__ Wd2,
                             const float* __restrict__ as2, const float* __restrict__ ad2,
                             const float* __restrict__ b2,
                             u16* __restrict__ Wfrag, float* __restrict__ bperm) {
    const int bid = blockIdx.x;
    const int layer = bid >> 3, r = bid & 7, r1 = r ^ 1;
    const float* Ws  = (layer ? Ws2 : Ws1) + (size_t)r  * 16384;
    const float* asp = (layer ? as2 : as1) + r  * 128;
    const float* Wdr = (layer ? Wd2 : Wd1) + (size_t)r1 * 16384;
    const float* adr = (layer ? ad2 : ad1) + r1 * 128;
    const float* bb  = (layer ? b2  : b1 ) + r  * 128;
    u16* wf = Wfrag + (size_t)bid * 18432;
    for (int f = threadIdx.x; f < 18432; f += blockDim.x) {
        int be   = f & 7;
        int lane = (f >> 3) & 63;
        int kc   = (f >> 9) & 3;
        int ct   = f >> 11;
        int k    = kc * 32 + (lane >> 4) * 8 + be;
        int krow = layer ? (((k & 7) << 4) | (k >> 3)) : k;
        int c    = lane & 15;
        float val;
        if (ct < 8) {
            val = Ws[(size_t)krow * 128 + ct * 16 + c];
        } else if (c < 4) {
            float s = 0.f;
            #pragma unroll
            for (int cc = 0; cc < 32; ++cc) s += Ws[(size_t)krow * 128 + c * 32 + cc] * asp[c * 32 + cc];
            val = s;
        } else if (c < 8) {
            int h = c - 4;
            float s = 0.f;
            #pragma unroll
            for (int cc = 0; cc < 32; ++cc) s += Wdr[(size_t)krow * 128 + h * 32 + cc] * adr[h * 32 + cc];
            val = s;
        } else {
            val = 0.f;
        }
        wf[f] = f2bf(val);
    }
    if (threadIdx.x < 128) {
        int p = threadIdx.x;
        bperm[bid * 128 + p] = bb[((p & 7) << 4) | (p >> 3)];
    }
}

// ---------------- fp32 -> bf16 convert (8 elems/thread) ----------------
__global__ void conv_bf16(const float* __restrict__ in, u16* __restrict__ out, long n8) {
    long i = (long)blockIdx.x * blockDim.x + threadIdx.x;
    if (i >= n8) return;
    float4 v0 = ((const float4*)in)[i * 2];
    float4 v1 = ((const float4*)in)[i * 2 + 1];
    union { u16 u[8]; uint4 q; } pk;
    pk.u[0] = f2bf(v0.x); pk.u[1] = f2bf(v0.y); pk.u[2] = f2bf(v0.z); pk.u[3] = f2bf(v0.w);
    pk.u[4] = f2bf(v1.x); pk.u[5] = f2bf(v1.y); pk.u[6] = f2bf(v1.z); pk.u[7] = f2bf(v1.w);
    ((uint4*)out)[i] = pk.q;
}

// ---------------- batched MFMA GEMM (grid.y = relation in batch) ----------------
__global__ __launch_bounds__(256) void gemm_mfma(const u16* __restrict__ Xbf,
                                                 const u16* __restrict__ WfragL,
                                                 u16* __restrict__ Hs4,
                                                 float* __restrict__ es4,
                                                 float* __restrict__ ed4,
                                                 int rbase, int4 st, int N) {
    const int y = blockIdx.y;
    const int r = rbase + y;
    const int stype = (y == 0) ? st.x : (y == 1) ? st.y : (y == 2) ? st.z : st.w;
    const u16* X  = Xbf + (size_t)stype * N * 128;
    const u16* Wf = WfragL + (size_t)r * 18432;
    u16*   Hs = Hs4 + (size_t)(r & 3) * N * 128;
    float* es = es4 + (size_t)(r & 3) * N * 4;
    float* ed = ed4 + (size_t)((r ^ 1) & 3) * N * 4;

    __shared__ u16 wlds[18432];
    const int tid = threadIdx.x;
    for (int i = tid; i < 2304; i += 256)
        ((s16x8*)wlds)[i] = ((const s16x8*)Wf)[i];

    const int wv = tid >> 6, l = tid & 63;
    const int lr = l & 15, lk = l >> 4;
    const int r0 = blockIdx.x * 128 + wv * 32;

    s16x8 af[2][4];
    #pragma unroll
    for (int rt = 0; rt < 2; ++rt) {
        int row = r0 + rt * 16 + lr;
        if (row > N - 1) row = N - 1;
        const s16x8* xp = (const s16x8*)(X + (size_t)row * 128 + lk * 8);
        af[rt][0] = xp[0]; af[rt][1] = xp[4]; af[rt][2] = xp[8]; af[rt][3] = xp[12];
    }
    __syncthreads();

    f32x4 acc[2][9] = {};
    #pragma unroll
    for (int ct = 0; ct < 9; ++ct) {
        s16x8 bf0 = ((s16x8*)wlds)[(ct * 4 + 0) * 64 + l];
        s16x8 bf1 = ((s16x8*)wlds)[(ct * 4 + 1) * 64 + l];
        s16x8 bf2 = ((s16x8*)wlds)[(ct * 4 + 2) * 64 + l];
        s16x8 bf3 = ((s16x8*)wlds)[(ct * 4 + 3) * 64 + l];
        #pragma unroll
        for (int rt = 0; rt < 2; ++rt) {
            acc[rt][ct] = __builtin_amdgcn_mfma_f32_16x16x32_bf16(af[rt][0], bf0, acc[rt][ct], 0, 0, 0);
            acc[rt][ct] = __builtin_amdgcn_mfma_f32_16x16x32_bf16(af[rt][1], bf1, acc[rt][ct], 0, 0, 0);
            acc[rt][ct] = __builtin_amdgcn_mfma_f32_16x16x32_bf16(af[rt][2], bf2, acc[rt][ct], 0, 0, 0);
            acc[rt][ct] = __builtin_amdgcn_mfma_f32_16x16x32_bf16(af[rt][3], bf3, acc[rt][ct], 0, 0, 0);
        }
    }

    #pragma unroll
    for (int rt = 0; rt < 2; ++rt) {
        #pragma unroll
        for (int j = 0; j < 4; ++j) {
            int row = r0 + rt * 16 + lk * 4 + j;
            if (row < N) {
                union { u16 u[8]; uint4 q; } pk;
                #pragma unroll
                for (int ct = 0; ct < 8; ++ct) pk.u[ct] = f2bf(acc[rt][ct][j]);
                *(uint4*)(Hs + (size_t)row * 128 + lr * 8) = pk.q;
                float evv = acc[rt][8][j];
                if (lr < 4)      es[(size_t)row * 4 + lr]     = evv;
                else if (lr < 8) ed[(size_t)row * 4 + lr - 4] = evv;
            }
        }
    }
}

// ---------------- CSR build (XCD-local: blockIdx%8 = relation) ----------------
__global__ void hist_kernel(const int* __restrict__ edges, int* __restrict__ counts,
                            int E, int N) {
    int r = blockIdx.x & 7;
    int e = (blockIdx.x >> 3) * 256 + threadIdx.x;
    if (e >= E) return;
    int d = edges[(size_t)r * 2 * E + E + e];
    atomicAdd(&counts[r * N + d], 1);
}

__global__ __launch_bounds__(256) void scan_block_k(const int* __restrict__ in,
                                                    int* __restrict__ outv,
                                                    int* __restrict__ bsum, int M) {
    __shared__ int sh[256];
    int t = threadIdx.x;
    int base = blockIdx.x * 2048 + t * 8;
    int vals[8];
    int tot = 0;
    #pragma unroll
    for (int j = 0; j < 8; ++j) {
        int v = (base + j < M) ? in[base + j] : 0;
        vals[j] = tot; tot += v;
    }
    sh[t] = tot;
    __syncthreads();
    for (int ofs = 1; ofs < 256; ofs <<= 1) {
        int y = 0;
        if (t >= ofs) y = sh[t - ofs];
        __syncthreads();
        if (t >= ofs) sh[t] += y;
        __syncthreads();
    }
    int ex = (t == 0) ? 0 : sh[t - 1];
    #pragma unroll
    for (int j = 0; j < 8; ++j)
        if (base + j < M) outv[base + j] = ex + vals[j];
    if (t == 255) bsum[blockIdx.x] = sh[255];
}

__global__ __launch_bounds__(1024) void scan_tops_k(const int* __restrict__ bsum,
                                                    int* __restrict__ bpref, int nb) {
    __shared__ int sh[1024];
    int t = threadIdx.x;
    int v = (t < nb) ? bsum[t] : 0;
    sh[t] = v;
    __syncthreads();
    for (int ofs = 1; ofs < 1024; ofs <<= 1) {
        int y = 0;
        if (t >= ofs) y = sh[t - ofs];
        __syncthreads();
        if (t >= ofs) sh[t] += y;
        __syncthreads();
    }
    if (t < nb) bpref[t] = sh[t] - v;
}

__global__ void scan_add_k(int* __restrict__ outv, const int* __restrict__ bpref, int M) {
    int g = blockIdx.x * blockDim.x + threadIdx.x;
    if (g < M) outv[g] += bpref[g >> 11];
}

__global__ void build_csr_k(const int* __restrict__ edges, int* __restrict__ pos,
                            int* __restrict__ srcs, int E, int N) {
    int r = blockIdx.x & 7;
    int e = (blockIdx.x >> 3) * 256 + threadIdx.x;
    if (e >= E) return;
    const int* b = edges + (size_t)r * 2 * E;
    int s = b[e], d = b[E + e];
    int idx = atomicAdd(&pos[r * N + d], 1);
    srcs[idx] = s;
}

// ---------------- pnorm: per-(dst,head) softmax -> normalized p in CSR order ----
// one thread per (dst,head); 4 relations per launch (blockIdx.y = slot)
__global__ __launch_bounds__(256) void pnorm_k(
        const int* __restrict__ srcsG, const int* __restrict__ offs,
        const int* __restrict__ counts, const float* __restrict__ es4,
        const float* __restrict__ ed4, float* __restrict__ pcsr,
        int rbase, int N) {
    const int y = blockIdx.y;
    const int r = rbase + y;
    const int* OFF = offs + (size_t)r * N;
    const int* CNT = counts + (size_t)r * N;
    const float* ES = es4 + (size_t)y * N * 4;
    const float* ED = ed4 + (size_t)y * N * 4;
    int g = blockIdx.x * 256 + threadIdx.x;
    if (g >= N * 4) return;
    const int d = g >> 2, h = g & 3;
    const int o0 = OFF[d], dg = CNT[d];
    if (dg == 0) return;
    const float edv = ED[(size_t)d * 4 + h];
    float lc[8];
    float mx = -INFINITY;
    #pragma unroll
    for (int i = 0; i < 8; ++i) {
        if (i < dg) {
            int s = srcsG[o0 + i];
            float lv = ES[(size_t)s * 4 + h] + edv;
            lv = lv > 0.f ? lv : 0.2f * lv;
            lc[i] = lv;
            mx = fmaxf(mx, lv);
        }
    }
    for (int i = 8; i < dg; ++i) {
        int s = srcsG[o0 + i];
        float lv = ES[(size_t)s * 4 + h] + edv;
        lv = lv > 0.f ? lv : 0.2f * lv;
        mx = fmaxf(mx, lv);
    }
    float den = 0.f;
    #pragma unroll
    for (int i = 0; i < 8; ++i) {
        if (i < dg) { lc[i] = __expf(lc[i] - mx); den += lc[i]; }
    }
    for (int i = 8; i < dg; ++i) {
        int s = srcsG[o0 + i];
        float lv = ES[(size_t)s * 4 + h] + edv;
        lv = lv > 0.f ? lv : 0.2f * lv;
        den += __expf(lv - mx);
    }
    const float inv = 1.f / (den + 1e-16f);
    #pragma unroll
    for (int i = 0; i < 8; ++i) {
        if (i < dg) pcsr[(size_t)(o0 + i) * 4 + h] = lc[i] * inv;
    }
    for (int i = 8; i < dg; ++i) {
        int s = srcsG[o0 + i];
        float lv = ES[(size_t)s * 4 + h] + edv;
        lv = lv > 0.f ? lv : 0.2f * lv;
        pcsr[(size_t)(o0 + i) * 4 + h] = __expf(lv - mx) * inv;
    }
}

// ---------------- fused gather (one-pass, p precomputed) ----------------
// OUT_MODE: 0 = ELU->bf16 (perm layout, to Xbf slice)
//           1 = raw fp32 perm (partial scratch)
//           2 = ELU fp32 un-permuted (final d_out slice)
// ACC: add partial scratch (perm fp32) before epilogue
template<int NR, int OUT_MODE, int ACC>
__global__ __launch_bounds__(256) void gat_gather(
        const int* __restrict__ srcsG, const float* __restrict__ pcsr,
        const int* __restrict__ offA, const int* __restrict__ cntA,
        const u16* __restrict__ HsA, const float* __restrict__ bpA,
        const int* __restrict__ offB, const int* __restrict__ cntB,
        const u16* __restrict__ HsB, const float* __restrict__ bpB,
        void* __restrict__ outA, void* __restrict__ outB,
        const float* __restrict__ part, int N) {
    const int lane = threadIdx.x & 63;
    const int d    = (blockIdx.x * 256 + threadIdx.x) >> 6;
    if (d >= N) return;
    const int h = lane & 3;
    const int pick = (NR == 1) ? blockIdx.y : 0;

    float a0 = 0.f, a1 = 0.f;

    #pragma unroll
    for (int rr = 0; rr < NR; ++rr) {
        const bool useB = (NR == 2) ? (rr == 1) : (pick == 1);
        const int* OFF  = useB ? offB : offA;
        const int* CNT  = useB ? cntB : cntA;
        const u16* HS   = useB ? HsB  : HsA;

        const int o0 = OFF[d], dg = CNT[d];
        #pragma unroll
        for (int i = 0; i < 8; ++i) {
            if (i < dg) {
                int s   = srcsG[o0 + i];
                float p = pcsr[(size_t)(o0 + i) * 4 + h];
                u32 hv  = *(const u32*)(HS + (size_t)s * 128 + 2 * lane);
                a0 += p * bf2f((u16)(hv & 0xFFFF));
                a1 += p * bf2f((u16)(hv >> 16));
            }
        }
        for (int i = 8; i < dg; ++i) {
            int s   = srcsG[o0 + i];
            float p = pcsr[(size_t)(o0 + i) * 4 + h];
            u32 hv  = *(const u32*)(HS + (size_t)s * 128 + 2 * lane);
            a0 += p * bf2f((u16)(hv & 0xFFFF));
            a1 += p * bf2f((u16)(hv >> 16));
        }
    }

    const float* bb = (NR == 1 && pick == 1) ? bpB : bpA;
    float b0 = bb[2 * lane], b1v = bb[2 * lane + 1];
    if (NR == 2) { b0 += bpB[2 * lane]; b1v += bpB[2 * lane + 1]; }
    a0 += b0; a1 += b1v;
    if (ACC) {
        float2 pv = *(const float2*)(part + (size_t)d * 128 + 2 * lane);
        a0 += pv.x; a1 += pv.y;
    }
    void* OP = (NR == 1 && pick == 1) ? outB : outA;
    if (OUT_MODE == 0) {
        u32 pk = (u32)f2bf(eluf(a0)) | ((u32)f2bf(eluf(a1)) << 16);
        *(u32*)((u16*)OP + (size_t)d * 128 + 2 * lane) = pk;
    } else if (OUT_MODE == 1) {
        *(float2*)((float*)OP + (size_t)d * 128 + 2 * lane) = make_float2(a0, a1);
    } else {
        float* o = (float*)OP + (size_t)d * 128;
        int p0 = 2 * lane, p1 = 2 * lane + 1;
        o[(p0 >> 3) | ((p0 & 7) << 4)] = eluf(a0);
        o[(p1 >> 3) | ((p1 & 7) << 4)] = eluf(a1);
    }
}

extern "C" void kernel_launch(void* const* d_in, const int* in_sizes, int n_in,
                              void* d_out, int out_size, void* d_ws, size_t ws_size,
                              hipStream_t stream) {
    const int N = in_sizes[0] / 128;
    const int E = in_sizes[5] / (2 * NRELS);

    const float* xs0[5] = { (const float*)d_in[0], (const float*)d_in[1],
                            (const float*)d_in[2], (const float*)d_in[3],
                            (const float*)d_in[4] };
    const int*   edges = (const int*)d_in[5];
    const float* Ws1 = (const float*)d_in[6];
    const float* Wd1 = (const float*)d_in[7];
    const float* as1 = (const float*)d_in[8];
    const float* ad1 = (const float*)d_in[9];
    const float* b1  = (const float*)d_in[10];
    const float* Ws2 = (const float*)d_in[11];
    const float* Wd2 = (const float*)d_in[12];
    const float* as2 = (const float*)d_in[13];
    const float* ad2 = (const float*)d_in[14];
    const float* b2  = (const float*)d_in[15];
    float* out = (float*)d_out;

    // workspace layout (~353 MB)
    char* wp = (char*)d_ws;
    u16*   Xbf   = (u16*)wp;   wp += (size_t)5 * N * 128 * 2;
    u16*   Hs4   = (u16*)wp;   wp += (size_t)4 * N * 128 * 2;
    float* es4   = (float*)wp; wp += (size_t)4 * N * 4 * 4;
    float* ed4   = (float*)wp; wp += (size_t)4 * N * 4 * 4;
    float* part  = (float*)wp; wp += (size_t)N * 128 * 4;
    float* pcsr  = (float*)wp; wp += (size_t)NRELS * E * 4 * 4;
    int* counts  = (int*)wp;   wp += (size_t)NRELS * N * 4;
    int* offs    = (int*)wp;   wp += (size_t)NRELS * N * 4;
    int* pos     = (int*)wp;   wp += (size_t)NRELS * N * 4;
    int* srcs    = (int*)wp;   wp += (size_t)NRELS * E * 4;
    u16* Wfrag   = (u16*)wp;   wp += (size_t)16 * 18432 * 2;
    float* bperm = (float*)wp; wp += (size_t)16 * 128 * 4;
    int* bsum    = (int*)wp;   wp += 1024 * 4;
    int* bpref   = (int*)wp;   wp += 1024 * 4;
    const size_t ws_used = (size_t)(wp - (char*)d_ws);
    if (ws_used > ws_size) return;

    // ---- re-establish the validated zero initial state on EVERY call ----
    hipMemsetAsync(d_ws, 0, ws_used, stream);
    hipMemsetAsync(d_out, 0, (size_t)5 * N * 128 * 4, stream);

    // ---- weight prep ----
    prep_weights<<<dim3(16), 256, 0, stream>>>(Ws1, Wd1, as1, ad1, b1,
                                               Ws2, Wd2, as2, ad2, b2, Wfrag, bperm);

    // ---- build CSR (dst-sorted), XCD-local ----
    const int M  = NRELS * N;
    const int nb = (M + 2047) / 2048;
    const int eblocks = 8 * ((E + 255) / 256);
    hist_kernel<<<dim3(eblocks), 256, 0, stream>>>(edges, counts, E, N);
    scan_block_k<<<dim3(nb), 256, 0, stream>>>(counts, offs, bsum, M);
    scan_tops_k<<<dim3(1), 1024, 0, stream>>>(bsum, bpref, nb);
    scan_add_k<<<dim3((M + 255) / 256), 256, 0, stream>>>(offs, bpref, M);
    hipMemcpyAsync(pos, offs, (size_t)M * 4, hipMemcpyDeviceToDevice, stream);
    build_csr_k<<<dim3(eblocks), 256, 0, stream>>>(edges, pos, srcs, E, N);

    // ---- convert inputs to bf16 ----
    const long n8type = (long)N * 128 / 8;
    for (int t = 0; t < 5; ++t)
        conv_bf16<<<dim3((int)((n8type + 255) / 256)), 256, 0, stream>>>(
            xs0[t], Xbf + (size_t)t * N * 128, n8type);

    const int gemmBlocks  = (N + 127) / 128;
    const int gBlocks     = (N + 3) / 4;
    const int pnormBlocks = (N * 4 + 255) / 256;

    // per-relation slot helpers
    #define OFFR(r)  (offs   + (size_t)(r) * N)
    #define CNTR(r)  (counts + (size_t)(r) * N)
    #define HSR(r)   (Hs4 + (size_t)((r) & 3) * N * 128)

    for (int layer = 0; layer < 2; ++layer) {
        const u16*   WL = Wfrag + (size_t)layer * 8 * 18432;
        const float* bL = bperm + layer * 8 * 128;

        // ===== batch A: relations 0..3 (src types 0,1,0,2) =====
        gemm_mfma<<<dim3(gemmBlocks, 4), 256, 0, stream>>>(
            Xbf, WL, Hs4, es4, ed4, 0, make_int4(0, 1, 0, 2), N);
        pnorm_k<<<dim3(pnormBlocks, 4), 256, 0, stream>>>(
            srcs, offs, counts, es4, ed4, pcsr, 0, N);
        // singles: r0 -> dst type 1, r2 -> dst type 2
        if (layer == 0)
            gat_gather<1, 0, 0><<<dim3(gBlocks, 2), 256, 0, stream>>>(
                srcs, pcsr, OFFR(0), CNTR(0), HSR(0), bL + 0 * 128,
                OFFR(2), CNTR(2), HSR(2), bL + 2 * 128,
                Xbf + (size_t)1 * N * 128, Xbf + (size_t)2 * N * 128, nullptr, N);
        else
            gat_gather<1, 2, 0><<<dim3(gBlocks, 2), 256, 0, stream>>>(
                srcs, pcsr, OFFR(0), CNTR(0), HSR(0), bL + 0 * 128,
                OFFR(2), CNTR(2), HSR(2), bL + 2 * 128,
                out + (size_t)1 * N * 128, out + (size_t)2 * N * 128, nullptr, N);
        // fused r1,r3 -> dst type 0 partial (perm fp32)
        gat_gather<2, 1, 0><<<dim3(gBlocks, 1), 256, 0, stream>>>(
            srcs, pcsr, OFFR(1), CNTR(1), HSR(1), bL + 1 * 128,
            OFFR(3), CNTR(3), HSR(3), bL + 3 * 128,
            part, nullptr, nullptr, N);

        // ===== batch B: relations 4..7 (src types 0,3,0,4) =====
        gemm_mfma<<<dim3(gemmBlocks, 4), 256, 0, stream>>>(
            Xbf, WL, Hs4, es4, ed4, 4, make_int4(0, 3, 0, 4), N);
        pnorm_k<<<dim3(pnormBlocks, 4), 256, 0, stream>>>(
            srcs, offs, counts, es4, ed4, pcsr, 4, N);
        // singles: r4 -> dst type 3, r6 -> dst type 4
        if (layer == 0)
            gat_gather<1, 0, 0><<<dim3(gBlocks, 2), 256, 0, stream>>>(
                srcs, pcsr, OFFR(4), CNTR(4), HSR(4), bL + 4 * 128,
                OFFR(6), CNTR(6), HSR(6), bL + 6 * 128,
                Xbf + (size_t)3 * N * 128, Xbf + (size_t)4 * N * 128, nullptr, N);
        else
            gat_gather<1, 2, 0><<<dim3(gBlocks, 2), 256, 0, stream>>>(
                srcs, pcsr, OFFR(4), CNTR(4), HSR(4), bL + 4 * 128,
                OFFR(6), CNTR(6), HSR(6), bL + 6 * 128,
                out + (size_t)3 * N * 128, out + (size_t)4 * N * 128, nullptr, N);
        // fused r5,r7 + partial -> dst type 0
        if (layer == 0)
            gat_gather<2, 0, 1><<<dim3(gBlocks, 1), 256, 0, stream>>>(
                srcs, pcsr, OFFR(5), CNTR(5), HSR(5), bL + 5 * 128,
                OFFR(7), CNTR(7), HSR(7), bL + 7 * 128,
                Xbf + (size_t)0 * N * 128, nullptr, part, N);
        else
            gat_gather<2, 2, 1><<<dim3(gBlocks, 1), 256, 0, stream>>>(
                srcs, pcsr, OFFR(5), CNTR(5), HSR(5), bL + 5 * 128,
                OFFR(7), CNTR(7), HSR(7), bL + 7 * 128,
                out + (size_t)0 * N * 128, nullptr, part, N);
    }
    #undef OFFR
    #undef CNTR
    #undef HSR
}

// Round 8
// 1107.336 us; speedup vs baseline: 1.5502x; 1.3585x over previous
//
#include <hip/hip_runtime.h>

#define NRELS 8
typedef __attribute__((ext_vector_type(8))) short s16x8;
typedef __attribute__((ext_vector_type(4))) float f32x4;
typedef unsigned short u16;
typedef unsigned int u32;

__device__ __forceinline__ u16 f2bf(float v) {
    unsigned u = __float_as_uint(v);
    u += 0x7FFFu + ((u >> 16) & 1u);
    return (u16)(u >> 16);
}
__device__ __forceinline__ float bf2f(u16 h) {
    return __uint_as_float(((unsigned)h) << 16);
}
__device__ __forceinline__ float eluf(float x) { return x > 0.f ? x : __expf(x) - 1.f; }

// ---------------- weight prep: fragment-major bf16 W (9 col-tiles) + permuted bias ----
__global__ void prep_weights(const float* __restrict__ Ws1, const float* __restrict__ Wd1,
                             const float* __restrict__ as1, const float* __restrict__ ad1,
                             const float* __restrict__ b1,
                             const float* __restrict__ Ws2, const float* __restrict__ Wd2,
                             const float* __restrict__ as2, const float* __restrict__ ad2,
                             const float* __restrict__ b2,
                             u16* __restrict__ Wfrag, float* __restrict__ bperm) {
    const int bid = blockIdx.x;
    const int layer = bid >> 3, r = bid & 7, r1 = r ^ 1;
    const float* Ws  = (layer ? Ws2 : Ws1) + (size_t)r  * 16384;
    const float* asp = (layer ? as2 : as1) + r  * 128;
    const float* Wdr = (layer ? Wd2 : Wd1) + (size_t)r1 * 16384;
    const float* adr = (layer ? ad2 : ad1) + r1 * 128;
    const float* bb  = (layer ? b2  : b1 ) + r  * 128;
    u16* wf = Wfrag + (size_t)bid * 18432;
    for (int f = threadIdx.x; f < 18432; f += blockDim.x) {
        int be   = f & 7;
        int lane = (f >> 3) & 63;
        int kc   = (f >> 9) & 3;
        int ct   = f >> 11;
        int k    = kc * 32 + (lane >> 4) * 8 + be;
        int krow = layer ? (((k & 7) << 4) | (k >> 3)) : k;
        int c    = lane & 15;
        float val;
        if (ct < 8) {
            val = Ws[(size_t)krow * 128 + ct * 16 + c];
        } else if (c < 4) {
            float s = 0.f;
            #pragma unroll
            for (int cc = 0; cc < 32; ++cc) s += Ws[(size_t)krow * 128 + c * 32 + cc] * asp[c * 32 + cc];
            val = s;
        } else if (c < 8) {
            int h = c - 4;
            float s = 0.f;
            #pragma unroll
            for (int cc = 0; cc < 32; ++cc) s += Wdr[(size_t)krow * 128 + h * 32 + cc] * adr[h * 32 + cc];
            val = s;
        } else {
            val = 0.f;
        }
        wf[f] = f2bf(val);
    }
    if (threadIdx.x < 128) {
        int p = threadIdx.x;
        bperm[bid * 128 + p] = bb[((p & 7) << 4) | (p >> 3)];
    }
}

// ---------------- fp32 -> bf16 convert (8 elems/thread) ----------------
__global__ void conv_bf16(const float* __restrict__ in, u16* __restrict__ out, long n8) {
    long i = (long)blockIdx.x * blockDim.x + threadIdx.x;
    if (i >= n8) return;
    float4 v0 = ((const float4*)in)[i * 2];
    float4 v1 = ((const float4*)in)[i * 2 + 1];
    union { u16 u[8]; uint4 q; } pk;
    pk.u[0] = f2bf(v0.x); pk.u[1] = f2bf(v0.y); pk.u[2] = f2bf(v0.z); pk.u[3] = f2bf(v0.w);
    pk.u[4] = f2bf(v1.x); pk.u[5] = f2bf(v1.y); pk.u[6] = f2bf(v1.z); pk.u[7] = f2bf(v1.w);
    ((uint4*)out)[i] = pk.q;
}

// ---------------- batched MFMA GEMM (grid.y = relation in batch) ----------------
__global__ __launch_bounds__(256) void gemm_mfma(const u16* __restrict__ Xbf,
                                                 const u16* __restrict__ WfragL,
                                                 u16* __restrict__ Hs4,
                                                 float* __restrict__ es4,
                                                 float* __restrict__ ed4,
                                                 int rbase, int4 st, int N) {
    const int y = blockIdx.y;
    const int r = rbase + y;
    const int stype = (y == 0) ? st.x : (y == 1) ? st.y : (y == 2) ? st.z : st.w;
    const u16* X  = Xbf + (size_t)stype * N * 128;
    const u16* Wf = WfragL + (size_t)r * 18432;
    u16*   Hs = Hs4 + (size_t)(r & 3) * N * 128;
    float* es = es4 + (size_t)(r & 3) * N * 4;
    float* ed = ed4 + (size_t)((r ^ 1) & 3) * N * 4;

    __shared__ u16 wlds[18432];
    const int tid = threadIdx.x;
    for (int i = tid; i < 2304; i += 256)
        ((s16x8*)wlds)[i] = ((const s16x8*)Wf)[i];

    const int wv = tid >> 6, l = tid & 63;
    const int lr = l & 15, lk = l >> 4;
    const int r0 = blockIdx.x * 128 + wv * 32;

    s16x8 af[2][4];
    #pragma unroll
    for (int rt = 0; rt < 2; ++rt) {
        int row = r0 + rt * 16 + lr;
        if (row > N - 1) row = N - 1;
        const s16x8* xp = (const s16x8*)(X + (size_t)row * 128 + lk * 8);
        af[rt][0] = xp[0]; af[rt][1] = xp[4]; af[rt][2] = xp[8]; af[rt][3] = xp[12];
    }
    __syncthreads();

    f32x4 acc[2][9] = {};
    #pragma unroll
    for (int ct = 0; ct < 9; ++ct) {
        s16x8 bf0 = ((s16x8*)wlds)[(ct * 4 + 0) * 64 + l];
        s16x8 bf1 = ((s16x8*)wlds)[(ct * 4 + 1) * 64 + l];
        s16x8 bf2 = ((s16x8*)wlds)[(ct * 4 + 2) * 64 + l];
        s16x8 bf3 = ((s16x8*)wlds)[(ct * 4 + 3) * 64 + l];
        #pragma unroll
        for (int rt = 0; rt < 2; ++rt) {
            acc[rt][ct] = __builtin_amdgcn_mfma_f32_16x16x32_bf16(af[rt][0], bf0, acc[rt][ct], 0, 0, 0);
            acc[rt][ct] = __builtin_amdgcn_mfma_f32_16x16x32_bf16(af[rt][1], bf1, acc[rt][ct], 0, 0, 0);
            acc[rt][ct] = __builtin_amdgcn_mfma_f32_16x16x32_bf16(af[rt][2], bf2, acc[rt][ct], 0, 0, 0);
            acc[rt][ct] = __builtin_amdgcn_mfma_f32_16x16x32_bf16(af[rt][3], bf3, acc[rt][ct], 0, 0, 0);
        }
    }

    #pragma unroll
    for (int rt = 0; rt < 2; ++rt) {
        #pragma unroll
        for (int j = 0; j < 4; ++j) {
            int row = r0 + rt * 16 + lk * 4 + j;
            if (row < N) {
                union { u16 u[8]; uint4 q; } pk;
                #pragma unroll
                for (int ct = 0; ct < 8; ++ct) pk.u[ct] = f2bf(acc[rt][ct][j]);
                *(uint4*)(Hs + (size_t)row * 128 + lr * 8) = pk.q;
                float evv = acc[rt][8][j];
                if (lr < 4)      es[(size_t)row * 4 + lr]     = evv;
                else if (lr < 8) ed[(size_t)row * 4 + lr - 4] = evv;
            }
        }
    }
}

// ---------------- CSR build (XCD-local: blockIdx%8 = relation) ----------------
__global__ void hist_kernel(const int* __restrict__ edges, int* __restrict__ counts,
                            int E, int N) {
    int r = blockIdx.x & 7;
    int e = (blockIdx.x >> 3) * 256 + threadIdx.x;
    if (e >= E) return;
    int d = edges[(size_t)r * 2 * E + E + e];
    atomicAdd(&counts[r * N + d], 1);
}

__global__ __launch_bounds__(256) void scan_block_k(const int* __restrict__ in,
                                                    int* __restrict__ outv,
                                                    int* __restrict__ bsum, int M) {
    __shared__ int sh[256];
    int t = threadIdx.x;
    int base = blockIdx.x * 2048 + t * 8;
    int vals[8];
    int tot = 0;
    #pragma unroll
    for (int j = 0; j < 8; ++j) {
        int v = (base + j < M) ? in[base + j] : 0;
        vals[j] = tot; tot += v;
    }
    sh[t] = tot;
    __syncthreads();
    for (int ofs = 1; ofs < 256; ofs <<= 1) {
        int y = 0;
        if (t >= ofs) y = sh[t - ofs];
        __syncthreads();
        if (t >= ofs) sh[t] += y;
        __syncthreads();
    }
    int ex = (t == 0) ? 0 : sh[t - 1];
    #pragma unroll
    for (int j = 0; j < 8; ++j)
        if (base + j < M) outv[base + j] = ex + vals[j];
    if (t == 255) bsum[blockIdx.x] = sh[255];
}

__global__ __launch_bounds__(1024) void scan_tops_k(const int* __restrict__ bsum,
                                                    int* __restrict__ bpref, int nb) {
    __shared__ int sh[1024];
    int t = threadIdx.x;
    int v = (t < nb) ? bsum[t] : 0;
    sh[t] = v;
    __syncthreads();
    for (int ofs = 1; ofs < 1024; ofs <<= 1) {
        int y = 0;
        if (t >= ofs) y = sh[t - ofs];
        __syncthreads();
        if (t >= ofs) sh[t] += y;
        __syncthreads();
    }
    if (t < nb) bpref[t] = sh[t] - v;
}

__global__ void scan_add_k(int* __restrict__ outv, const int* __restrict__ bpref, int M) {
    int g = blockIdx.x * blockDim.x + threadIdx.x;
    if (g < M) outv[g] += bpref[g >> 11];
}

__global__ void build_csr_k(const int* __restrict__ edges, int* __restrict__ pos,
                            int* __restrict__ srcs, int E, int N) {
    int r = blockIdx.x & 7;
    int e = (blockIdx.x >> 3) * 256 + threadIdx.x;
    if (e >= E) return;
    const int* b = edges + (size_t)r * 2 * E;
    int s = b[e], d = b[E + e];
    int idx = atomicAdd(&pos[r * N + d], 1);
    srcs[idx] = s;
}

// ---------------- pnorm: per-(dst,head) softmax -> normalized p in CSR order ----
__global__ __launch_bounds__(256) void pnorm_k(
        const int* __restrict__ srcsG, const int* __restrict__ offs,
        const int* __restrict__ counts, const float* __restrict__ es4,
        const float* __restrict__ ed4, float* __restrict__ pcsr,
        int rbase, int N) {
    const int y = blockIdx.y;
    const int r = rbase + y;
    const int* OFF = offs + (size_t)r * N;
    const int* CNT = counts + (size_t)r * N;
    const float* ES = es4 + (size_t)y * N * 4;
    const float* ED = ed4 + (size_t)y * N * 4;
    int g = blockIdx.x * 256 + threadIdx.x;
    if (g >= N * 4) return;
    const int d = g >> 2, h = g & 3;
    const int o0 = OFF[d], dg = CNT[d];
    if (dg == 0) return;
    const float edv = ED[(size_t)d * 4 + h];
    float lc[8];
    float mx = -INFINITY;
    #pragma unroll
    for (int i = 0; i < 8; ++i) {
        if (i < dg) {
            int s = srcsG[o0 + i];
            float lv = ES[(size_t)s * 4 + h] + edv;
            lv = lv > 0.f ? lv : 0.2f * lv;
            lc[i] = lv;
            mx = fmaxf(mx, lv);
        }
    }
    for (int i = 8; i < dg; ++i) {
        int s = srcsG[o0 + i];
        float lv = ES[(size_t)s * 4 + h] + edv;
        lv = lv > 0.f ? lv : 0.2f * lv;
        mx = fmaxf(mx, lv);
    }
    float den = 0.f;
    #pragma unroll
    for (int i = 0; i < 8; ++i) {
        if (i < dg) { lc[i] = __expf(lc[i] - mx); den += lc[i]; }
    }
    for (int i = 8; i < dg; ++i) {
        int s = srcsG[o0 + i];
        float lv = ES[(size_t)s * 4 + h] + edv;
        lv = lv > 0.f ? lv : 0.2f * lv;
        den += __expf(lv - mx);
    }
    const float inv = 1.f / (den + 1e-16f);
    #pragma unroll
    for (int i = 0; i < 8; ++i) {
        if (i < dg) pcsr[(size_t)(o0 + i) * 4 + h] = lc[i] * inv;
    }
    for (int i = 8; i < dg; ++i) {
        int s = srcsG[o0 + i];
        float lv = ES[(size_t)s * 4 + h] + edv;
        lv = lv > 0.f ? lv : 0.2f * lv;
        pcsr[(size_t)(o0 + i) * 4 + h] = __expf(lv - mx) * inv;
    }
}

// ---------------- fused gather: 16 lanes per dst, uint4 rows, 4x MLP ----------------
// lane ln covers perm positions 8ln..8ln+7 of its dst's row; head(pos 8ln+j) = j>>1.
// OUT_MODE: 0 = ELU->bf16 (perm layout, to Xbf slice)
//           1 = raw fp32 perm (partial scratch)
//           2 = ELU fp32 un-permuted (final d_out slice; orig col = (j<<4)|ln)
// ACC: add partial scratch (perm fp32) before epilogue
template<int NR, int OUT_MODE, int ACC>
__global__ __launch_bounds__(256) void gat_gather(
        const int* __restrict__ srcsG, const float* __restrict__ pcsr,
        const int* __restrict__ offA, const int* __restrict__ cntA,
        const u16* __restrict__ HsA, const float* __restrict__ bpA,
        const int* __restrict__ offB, const int* __restrict__ cntB,
        const u16* __restrict__ HsB, const float* __restrict__ bpB,
        void* __restrict__ outA, void* __restrict__ outB,
        const float* __restrict__ part, int N) {
    const int tid  = threadIdx.x;
    const int ln   = tid & 15;
    const int d    = (blockIdx.x * 256 + tid) >> 4;    // 16 dsts per block
    const int pick = (NR == 1) ? blockIdx.y : 0;
    const bool act = (d < N);
    const int dsafe = act ? d : 0;

    float a[8] = {};

    #pragma unroll
    for (int rr = 0; rr < NR; ++rr) {
        const bool useB = (NR == 2) ? (rr == 1) : (pick == 1);
        const int* OFF  = useB ? offB : offA;
        const int* CNT  = useB ? cntB : cntA;
        const u16* HS   = useB ? HsB  : HsA;

        const int o0 = OFF[dsafe];
        const int dg = act ? CNT[dsafe] : 0;

        #pragma unroll
        for (int i = 0; i < 8; ++i) {
            if (i < dg) {
                int s = srcsG[o0 + i];
                float4 p4 = *(const float4*)(pcsr + (size_t)(o0 + i) * 4);
                uint4 hv  = *(const uint4*)(HS + (size_t)s * 128 + 8 * ln);
                a[0] += p4.x * bf2f((u16)(hv.x & 0xFFFF));
                a[1] += p4.x * bf2f((u16)(hv.x >> 16));
                a[2] += p4.y * bf2f((u16)(hv.y & 0xFFFF));
                a[3] += p4.y * bf2f((u16)(hv.y >> 16));
                a[4] += p4.z * bf2f((u16)(hv.z & 0xFFFF));
                a[5] += p4.z * bf2f((u16)(hv.z >> 16));
                a[6] += p4.w * bf2f((u16)(hv.w & 0xFFFF));
                a[7] += p4.w * bf2f((u16)(hv.w >> 16));
            }
        }
        for (int i = 8; i < dg; ++i) {
            int s = srcsG[o0 + i];
            float4 p4 = *(const float4*)(pcsr + (size_t)(o0 + i) * 4);
            uint4 hv  = *(const uint4*)(HS + (size_t)s * 128 + 8 * ln);
            a[0] += p4.x * bf2f((u16)(hv.x & 0xFFFF));
            a[1] += p4.x * bf2f((u16)(hv.x >> 16));
            a[2] += p4.y * bf2f((u16)(hv.y & 0xFFFF));
            a[3] += p4.y * bf2f((u16)(hv.y >> 16));
            a[4] += p4.z * bf2f((u16)(hv.z & 0xFFFF));
            a[5] += p4.z * bf2f((u16)(hv.z >> 16));
            a[6] += p4.w * bf2f((u16)(hv.w & 0xFFFF));
            a[7] += p4.w * bf2f((u16)(hv.w >> 16));
        }
    }
    if (!act) return;

    const float* bb = (NR == 1 && pick == 1) ? bpB : bpA;
    float4 b0 = *(const float4*)(bb + 8 * ln);
    float4 b1 = *(const float4*)(bb + 8 * ln + 4);
    a[0] += b0.x; a[1] += b0.y; a[2] += b0.z; a[3] += b0.w;
    a[4] += b1.x; a[5] += b1.y; a[6] += b1.z; a[7] += b1.w;
    if (NR == 2) {
        float4 c0 = *(const float4*)(bpB + 8 * ln);
        float4 c1 = *(const float4*)(bpB + 8 * ln + 4);
        a[0] += c0.x; a[1] += c0.y; a[2] += c0.z; a[3] += c0.w;
        a[4] += c1.x; a[5] += c1.y; a[6] += c1.z; a[7] += c1.w;
    }
    if (ACC) {
        float4 q0 = *(const float4*)(part + (size_t)d * 128 + 8 * ln);
        float4 q1 = *(const float4*)(part + (size_t)d * 128 + 8 * ln + 4);
        a[0] += q0.x; a[1] += q0.y; a[2] += q0.z; a[3] += q0.w;
        a[4] += q1.x; a[5] += q1.y; a[6] += q1.z; a[7] += q1.w;
    }
    void* OP = (NR == 1 && pick == 1) ? outB : outA;
    if (OUT_MODE == 0) {
        union { u16 u[8]; uint4 q; } pk;
        #pragma unroll
        for (int j = 0; j < 8; ++j) pk.u[j] = f2bf(eluf(a[j]));
        *(uint4*)((u16*)OP + (size_t)d * 128 + 8 * ln) = pk.q;
    } else if (OUT_MODE == 1) {
        float4 w0 = make_float4(a[0], a[1], a[2], a[3]);
        float4 w1 = make_float4(a[4], a[5], a[6], a[7]);
        *(float4*)((float*)OP + (size_t)d * 128 + 8 * ln)     = w0;
        *(float4*)((float*)OP + (size_t)d * 128 + 8 * ln + 4) = w1;
    } else {
        float* o = (float*)OP + (size_t)d * 128;
        #pragma unroll
        for (int j = 0; j < 8; ++j)
            o[(j << 4) | ln] = eluf(a[j]);
    }
}

extern "C" void kernel_launch(void* const* d_in, const int* in_sizes, int n_in,
                              void* d_out, int out_size, void* d_ws, size_t ws_size,
                              hipStream_t stream) {
    const int N = in_sizes[0] / 128;
    const int E = in_sizes[5] / (2 * NRELS);

    const float* xs0[5] = { (const float*)d_in[0], (const float*)d_in[1],
                            (const float*)d_in[2], (const float*)d_in[3],
                            (const float*)d_in[4] };
    const int*   edges = (const int*)d_in[5];
    const float* Ws1 = (const float*)d_in[6];
    const float* Wd1 = (const float*)d_in[7];
    const float* as1 = (const float*)d_in[8];
    const float* ad1 = (const float*)d_in[9];
    const float* b1  = (const float*)d_in[10];
    const float* Ws2 = (const float*)d_in[11];
    const float* Wd2 = (const float*)d_in[12];
    const float* as2 = (const float*)d_in[13];
    const float* ad2 = (const float*)d_in[14];
    const float* b2  = (const float*)d_in[15];
    float* out = (float*)d_out;

    // workspace layout (~353 MB)
    char* wp = (char*)d_ws;
    u16*   Xbf   = (u16*)wp;   wp += (size_t)5 * N * 128 * 2;
    u16*   Hs4   = (u16*)wp;   wp += (size_t)4 * N * 128 * 2;
    float* es4   = (float*)wp; wp += (size_t)4 * N * 4 * 4;
    float* ed4   = (float*)wp; wp += (size_t)4 * N * 4 * 4;
    float* part  = (float*)wp; wp += (size_t)N * 128 * 4;
    float* pcsr  = (float*)wp; wp += (size_t)NRELS * E * 4 * 4;
    int* counts  = (int*)wp;   wp += (size_t)NRELS * N * 4;
    int* offs    = (int*)wp;   wp += (size_t)NRELS * N * 4;
    int* pos     = (int*)wp;   wp += (size_t)NRELS * N * 4;
    int* srcs    = (int*)wp;   wp += (size_t)NRELS * E * 4;
    u16* Wfrag   = (u16*)wp;   wp += (size_t)16 * 18432 * 2;
    float* bperm = (float*)wp; wp += (size_t)16 * 128 * 4;
    int* bsum    = (int*)wp;   wp += 1024 * 4;
    int* bpref   = (int*)wp;   wp += 1024 * 4;
    const size_t ws_used = (size_t)(wp - (char*)d_ws);
    if (ws_used > ws_size) return;

    // ---- re-establish the validated zero initial ws state on EVERY call ----
    // d_out needs no zeroing: every element is unconditionally overwritten by a
    // layer-2 OUT_MODE-2 gather (no read-modify-write on d_out).
    hipMemsetAsync(d_ws, 0, ws_used, stream);

    // ---- weight prep ----
    prep_weights<<<dim3(16), 256, 0, stream>>>(Ws1, Wd1, as1, ad1, b1,
                                               Ws2, Wd2, as2, ad2, b2, Wfrag, bperm);

    // ---- build CSR (dst-sorted), XCD-local ----
    const int M  = NRELS * N;
    const int nb = (M + 2047) / 2048;
    const int eblocks = 8 * ((E + 255) / 256);
    hist_kernel<<<dim3(eblocks), 256, 0, stream>>>(edges, counts, E, N);
    scan_block_k<<<dim3(nb), 256, 0, stream>>>(counts, offs, bsum, M);
    scan_tops_k<<<dim3(1), 1024, 0, stream>>>(bsum, bpref, nb);
    scan_add_k<<<dim3((M + 255) / 256), 256, 0, stream>>>(offs, bpref, M);
    hipMemcpyAsync(pos, offs, (size_t)M * 4, hipMemcpyDeviceToDevice, stream);
    build_csr_k<<<dim3(eblocks), 256, 0, stream>>>(edges, pos, srcs, E, N);

    // ---- convert inputs to bf16 ----
    const long n8type = (long)N * 128 / 8;
    for (int t = 0; t < 5; ++t)
        conv_bf16<<<dim3((int)((n8type + 255) / 256)), 256, 0, stream>>>(
            xs0[t], Xbf + (size_t)t * N * 128, n8type);

    const int gemmBlocks  = (N + 127) / 128;
    const int gBlocks     = (N + 15) / 16;   // 16 dsts per block
    const int pnormBlocks = (N * 4 + 255) / 256;

    // per-relation slot helpers
    #define OFFR(r)  (offs   + (size_t)(r) * N)
    #define CNTR(r)  (counts + (size_t)(r) * N)
    #define HSR(r)   (Hs4 + (size_t)((r) & 3) * N * 128)

    for (int layer = 0; layer < 2; ++layer) {
        const u16*   WL = Wfrag + (size_t)layer * 8 * 18432;
        const float* bL = bperm + layer * 8 * 128;

        // ===== batch A: relations 0..3 (src types 0,1,0,2) =====
        gemm_mfma<<<dim3(gemmBlocks, 4), 256, 0, stream>>>(
            Xbf, WL, Hs4, es4, ed4, 0, make_int4(0, 1, 0, 2), N);
        pnorm_k<<<dim3(pnormBlocks, 4), 256, 0, stream>>>(
            srcs, offs, counts, es4, ed4, pcsr, 0, N);
        // singles: r0 -> dst type 1, r2 -> dst type 2
        if (layer == 0)
            gat_gather<1, 0, 0><<<dim3(gBlocks, 2), 256, 0, stream>>>(
                srcs, pcsr, OFFR(0), CNTR(0), HSR(0), bL + 0 * 128,
                OFFR(2), CNTR(2), HSR(2), bL + 2 * 128,
                Xbf + (size_t)1 * N * 128, Xbf + (size_t)2 * N * 128, nullptr, N);
        else
            gat_gather<1, 2, 0><<<dim3(gBlocks, 2), 256, 0, stream>>>(
                srcs, pcsr, OFFR(0), CNTR(0), HSR(0), bL + 0 * 128,
                OFFR(2), CNTR(2), HSR(2), bL + 2 * 128,
                out + (size_t)1 * N * 128, out + (size_t)2 * N * 128, nullptr, N);
        // fused r1,r3 -> dst type 0 partial (perm fp32)
        gat_gather<2, 1, 0><<<dim3(gBlocks, 1), 256, 0, stream>>>(
            srcs, pcsr, OFFR(1), CNTR(1), HSR(1), bL + 1 * 128,
            OFFR(3), CNTR(3), HSR(3), bL + 3 * 128,
            part, nullptr, nullptr, N);

        // ===== batch B: relations 4..7 (src types 0,3,0,4) =====
        gemm_mfma<<<dim3(gemmBlocks, 4), 256, 0, stream>>>(
            Xbf, WL, Hs4, es4, ed4, 4, make_int4(0, 3, 0, 4), N);
        pnorm_k<<<dim3(pnormBlocks, 4), 256, 0, stream>>>(
            srcs, offs, counts, es4, ed4, pcsr, 4, N);
        // singles: r4 -> dst type 3, r6 -> dst type 4
        if (layer == 0)
            gat_gather<1, 0, 0><<<dim3(gBlocks, 2), 256, 0, stream>>>(
                srcs, pcsr, OFFR(4), CNTR(4), HSR(4), bL + 4 * 128,
                OFFR(6), CNTR(6), HSR(6), bL + 6 * 128,
                Xbf + (size_t)3 * N * 128, Xbf + (size_t)4 * N * 128, nullptr, N);
        else
            gat_gather<1, 2, 0><<<dim3(gBlocks, 2), 256, 0, stream>>>(
                srcs, pcsr, OFFR(4), CNTR(4), HSR(4), bL + 4 * 128,
                OFFR(6), CNTR(6), HSR(6), bL + 6 * 128,
                out + (size_t)3 * N * 128, out + (size_t)4 * N * 128, nullptr, N);
        // fused r5,r7 + partial -> dst type 0
        if (layer == 0)
            gat_gather<2, 0, 1><<<dim3(gBlocks, 1), 256, 0, stream>>>(
                srcs, pcsr, OFFR(5), CNTR(5), HSR(5), bL + 5 * 128,
                OFFR(7), CNTR(7), HSR(7), bL + 7 * 128,
                Xbf + (size_t)0 * N * 128, nullptr, part, N);
        else
            gat_gather<2, 2, 1><<<dim3(gBlocks, 1), 256, 0, stream>>>(
                srcs, pcsr, OFFR(5), CNTR(5), HSR(5), bL + 5 * 128,
                OFFR(7), CNTR(7), HSR(7), bL + 7 * 128,
                out + (size_t)0 * N * 128, nullptr, part, N);
    }
    #undef OFFR
    #undef CNTR
    #undef HSR
}